// Round 6
// baseline (397.460 us; speedup 1.0000x reference)
//
#include <hip/hip_runtime.h>

#define NV 15000
#define ND 16
#define NR 3
#define NC 32
#define NFDIM 64
#define BB 2

typedef short bf16x8 __attribute__((ext_vector_type(8)));
typedef float f32x4 __attribute__((ext_vector_type(4)));
typedef unsigned short u16x8 __attribute__((ext_vector_type(8)));
typedef unsigned int u32;

// ws layout (bytes):
//   y_t  bf16 [NV][16][2][32]          : 30,720,000
//   kb   bf16 [48][4][64][8]           :    196,608
//   zero pad (dummy gather line)       :        256
#define KB_OFF     30720000u
#define WS_NEEDED  30916864u

// Dummy offset in yt-shorts: points at the zeroed pad after kb.
#define DUMMY_OFF  15458304   // (KB_OFF + 196608) / 2
#define SPLIT_OFF  7680000    // 7500 * 1024  (vtx < 7500  <=>  pre < SPLIT_OFF)

#define AS1 __attribute__((address_space(1)))
#define AS3 __attribute__((address_space(3)))
#define GLOAD16(gp, lp) __builtin_amdgcn_global_load_lds((AS1 const u32*)(gp), (AS3 u32*)(lp), 16, 0, 0)

__device__ __forceinline__ unsigned short f2bf(float x) {
  union { float f; unsigned int u; } cv; cv.f = x;
  unsigned int u = cv.u;
  u += 0x7FFF + ((u >> 16) & 1);          // round to nearest even
  return (unsigned short)(u >> 16);
}

// y (B,NV,16,32) fp32 -> y_t (NV,16,B,32) bf16. One thread per 8 elems.
__global__ void prep_y(const float* __restrict__ y, u16x8* __restrict__ yt) {
  int tid = blockIdx.x * 256 + threadIdx.x;
  if (tid >= (NV * ND * BB * NC) / 8) return;
  int o   = tid * 8;
  int v   = o >> 10;
  int rem = o & 1023;
  int d   = rem >> 6;
  int b   = (rem >> 5) & 1;
  int c0  = rem & 31;
  const f32x4* src = (const f32x4*)(y + (((b * NV + v) * ND + d) * NC + c0));
  f32x4 lo = src[0], hi = src[1];
  u16x8 r;
#pragma unroll
  for (int i = 0; i < 4; i++) { r[i] = f2bf(lo[i]); r[4 + i] = f2bf(hi[i]); }
  yt[tid] = r;
}

// kernel (3,16,32,64) fp32 -> kb in MFMA B-fragment layout with f = 4*col+ft:
// kb[((chunk*4 + ft)*64 + lane)*8 + j] = kernel[chunk][k=(lane>>4)*8+j][f=(lane&15)*4+ft]
// Also zeroes the 256-B dummy-line pad after kb (gather target for masked lanes).
__global__ void prep_kb(const float* __restrict__ kern, unsigned short* __restrict__ kb) {
  int t = blockIdx.x * 256 + threadIdx.x;   // [0, 48*4*64)
  if (t < 128) kb[48 * 4 * 64 * 8 + t] = 0; // zero pad (128 shorts = 256 B)
  if (t >= 48 * 4 * 64) return;
  int lane  = t & 63;
  int ft    = (t >> 6) & 3;
  int chunk = t >> 8;
  int q = lane >> 4;
  int f = (lane & 15) * 4 + ft;
  unsigned short* dst = kb + t * 8;
#pragma unroll
  for (int j = 0; j < 8; j++) {
    int k = q * 8 + j;
    dst[j] = f2bf(kern[(chunk * NC + k) * NFDIM + f]);
  }
}

// R10: R8 structure + 2-phase vtx-split gather (L2 capacity lever).
//
// R9 post-mortem: register A-prefetch collapsed again (VGPR=56); but the
// concurrency arithmetic (16 waves/CU x ~32 lines in flight ≈ 16 MB chip-wide)
// rules out latency/MLP as the limit. Invariant across R0/R5/R6/R8/R9:
// dur == (FETCH+WRITE)/~3.7TB/s. The kernel is L2-MISS-BYTE-bound.
// Miss bytes = 1.47 GB gather demand x (1 - 56% L2 hit); hit rate is
// capacity-limited (30.7 MB random footprint vs 4 MB L2/XCD).
//
// Lever: run the K-reduction twice, pass 0 accumulating only entries with
// vtx < 7500 (pre < SPLIT_OFF), pass 1 the rest. Out-of-phase lanes redirect
// their gather address to a ZEROED hot dummy line (no fetch of the real line,
// exact 0 contribution to acc). Uniform block durations keep concurrent
// blocks generation-aligned, so the instantaneous gather footprint halves
// (~15.3 MB) -> L2 hit rate up -> FETCH down. Core prediction: FETCH
// 645 -> ~450-500 MB. If FETCH is unchanged, miss bytes are irreducible ->
// roofline.
//
// Per iter t (48 total, 24 per phase): [vmcnt(2): slot t%3 landed, next
// stage in flight] -> s_barrier -> A(t) gather (masked, direct to VGPR) ->
// stageB(t+2) into dead slot -> 8 ds_read_b128 + 16 MFMA (setprio).
__global__ __launch_bounds__(256, 4) void sync_conv_main(
    const unsigned short* __restrict__ yt, const unsigned short* __restrict__ kb,
    const int* __restrict__ ftv, const int* __restrict__ ftd,
    const float* __restrict__ bias, float* __restrict__ out) {
  // pidx is dead after phase 2 of the prologue; alias it over the B-ring.
  __shared__ union ShU {
    int   pidx[16][49];      //  3,136 B (prologue only)
    short ring[3 * 4096];    // 24,576 B (3 batch-slots x 8 KB)
  } sh;
  __shared__ int pre[4][16][49];   // per-wave rotated offsets  12,544 B

  int tid  = threadIdx.x;
  int lane = tid & 63;
  int w    = tid >> 6;
  int mg   = blockIdx.x >> 2;
  int lg   = blockIdx.x & 3;
  int l    = lg * 4 + w;
  int vbase = mg * 16;

  // prologue phase 1: packed indices
  for (int t = tid; t < 16 * 48; t += 256) {
    int i = t / 48, j = t - i * 48;
    int v = vbase + i; v = v < NV ? v : NV - 1;
    sh.pidx[i][j] = ftv[v * 48 + j] * 16 + (ftd[v * 48 + j] & 15);
  }
  __syncthreads();
  // prologue phase 2: per-l pre-rotated offsets: vtx*1024 + ((ftd+l)&15)*64
#pragma unroll
  for (int wl = 0; wl < 4; wl++) {
    int ll = lg * 4 + wl;
    for (int t = tid; t < 768; t += 256) {
      int i = t / 48, j = t - i * 48;
      int p = sh.pidx[i][j];
      pre[wl][i][j] = (p >> 4) * 1024 + ((((p & 15) + ll) & 15) << 6);
    }
  }
  __syncthreads();   // pidx dead beyond this point; ring may overwrite it

  int q    = lane >> 4;
  int n    = lane & 15;
  int voff = n >> 1;
  int lane_elem = (n & 1) * 32 + q * 8;     // shorts
  const int* pre_w0 = &pre[w][voff][0];
  const int* pre_w1 = &pre[w][8 + voff][0];

  f32x4 acc[2][4];
#pragma unroll
  for (int i = 0; i < 2; i++)
#pragma unroll
    for (int j = 0; j < 4; j++) acc[i][j] = (f32x4){0.f, 0.f, 0.f, 0.f};

  // Cooperative B-stage: ring-step t stages chunk pair (2*(t%24), +1); wave w
  // stages its 2 KB quarter as two 1 KB lane-linear gl_lds loads
  // (per-lane global stride 16 B == gl_lds lane stride; LDS base uniform).
  auto stageB = [&](int t, int slot) {
    int tt = t >= 24 ? t - 24 : t;
    const unsigned short* g = kb + tt * 4096 + w * 1024 + (lane << 3);
    short* dl = sh.ring + slot * 4096 + w * 1024;
    GLOAD16(g, dl);
    GLOAD16(g + 512, dl + 512);
  };

  // Prologue: slots 0 and 1 in flight.
  stageB(0, 0);
  stageB(1, 1);

  int sl = 0;                                  // slot of step t
#pragma unroll 3
  for (int t = 0; t < 48; t++) {
    if (t < 47) {
      asm volatile("s_waitcnt vmcnt(2)" ::: "memory");
    } else {
      asm volatile("s_waitcnt vmcnt(0)" ::: "memory");
    }
    __builtin_amdgcn_s_barrier();

    // Masked A gather for this step (direct to VGPR), phase = (t >= 24).
    bool ph = t >= 24;
    int tt = ph ? t - 24 : t;
    bf16x8 A[2][2];
#pragma unroll
    for (int ds = 0; ds < 2; ds++) {
      int s = 2 * tt + ds;
      int j = (s & 48) | ((s + l) & 15);       // r*16 + ((e+l)&15)
      int p0 = pre_w0[j];
      int p1 = pre_w1[j];
      bool ok0 = (p0 < SPLIT_OFF) != ph;       // in-phase?
      bool ok1 = (p1 < SPLIT_OFF) != ph;
      int o0 = ok0 ? p0 : DUMMY_OFF;           // dummy line is zeroed + hot
      int o1 = ok1 ? p1 : DUMMY_OFF;
      A[0][ds] = *reinterpret_cast<const bf16x8*>(yt + o0 + lane_elem);
      A[1][ds] = *reinterpret_cast<const bf16x8*>(yt + o1 + lane_elem);
    }

    if (t + 2 < 48) stageB(t + 2, sl == 0 ? 2 : sl - 1);   // (t+2)%3 == (t-1)%3

    const short* lb = sh.ring + sl * 4096;
    __builtin_amdgcn_s_setprio(1);
#pragma unroll
    for (int ds = 0; ds < 2; ds++) {
#pragma unroll
      for (int ft = 0; ft < 4; ft++) {
        bf16x8 bf = *reinterpret_cast<const bf16x8*>(lb + ds * 2048 + ft * 512 + (lane << 3));
        acc[0][ft] = __builtin_amdgcn_mfma_f32_16x16x32_bf16(A[0][ds], bf, acc[0][ft], 0, 0, 0);
        acc[1][ft] = __builtin_amdgcn_mfma_f32_16x16x32_bf16(A[1][ds], bf, acc[1][ft], 0, 0, 0);
      }
    }
    __builtin_amdgcn_s_setprio(0);
    sl = sl == 2 ? 0 : sl + 1;
  }

  f32x4 bv = *reinterpret_cast<const f32x4*>(bias + 4 * n);

#pragma unroll
  for (int mt = 0; mt < 2; mt++) {
#pragma unroll
    for (int reg = 0; reg < 4; reg++) {
      int m  = q * 4 + reg;
      int v  = vbase + mt * 8 + (m >> 1);
      int bb = m & 1;
      if (v < NV) {
        f32x4 x;
#pragma unroll
        for (int ft = 0; ft < 4; ft++) {
          float t = acc[mt][ft][reg] + bv[ft];   // f = 4n+ft
          x[ft] = t > 0.f ? t : 0.f;
        }
        float* dst = out + (((bb * NV + v) * ND + l) * NFDIM) + 4 * n;
        __builtin_nontemporal_store(x, (f32x4*)dst);
      }
    }
  }
}

// Slow fp32 fallback (only if ws too small).
__global__ void fallback_kernel(const float* __restrict__ y, const int* __restrict__ ftv,
                                const int* __restrict__ ftd, const float* __restrict__ kern,
                                const float* __restrict__ bias, float* __restrict__ out) {
  int idx = blockIdx.x;               // b*NV*16 + v*16 + l
  int l = idx & 15;
  int v = (idx >> 4) % NV;
  int b = idx / (NV * ND);
  int f = threadIdx.x;
  float acc = 0.f;
  for (int r = 0; r < NR; r++)
    for (int d = 0; d < ND; d++) {
      int ii = (v * NR + r) * ND + d;
      int vv = ftv[ii];
      int dd = (ftd[ii] + l) & 15;
      int dp = (d - l) & 15;
      const float* yp = y + ((b * NV + vv) * ND + dd) * NC;
      const float* kp = kern + ((r * 16 + dp) * NC) * NFDIM + f;
#pragma unroll 8
      for (int c = 0; c < NC; c++) acc += yp[c] * kp[c * NFDIM];
    }
  float x = acc + bias[f];
  out[idx * NFDIM + f] = x > 0.f ? x : 0.f;
}

extern "C" void kernel_launch(void* const* d_in, const int* in_sizes, int n_in,
                              void* d_out, int out_size, void* d_ws, size_t ws_size,
                              hipStream_t stream) {
  const float* y    = (const float*)d_in[0];
  const int*   ftv  = (const int*)d_in[1];
  const int*   ftd  = (const int*)d_in[2];
  const float* kern = (const float*)d_in[3];
  const float* bias = (const float*)d_in[4];
  float* out = (float*)d_out;

  if (ws_size >= (size_t)WS_NEEDED) {
    char* ws = (char*)d_ws;
    unsigned short* yt = (unsigned short*)ws;
    unsigned short* kb = (unsigned short*)(ws + KB_OFF);

    prep_y<<<(NV * ND * BB * NC / 8 + 255) / 256, 256, 0, stream>>>(y, (u16x8*)yt);
    prep_kb<<<(48 * 4 * 64 + 255) / 256, 256, 0, stream>>>(kern, kb);
    // 938 m-groups (16 v each) x 4 l-groups = 3752 blocks x 4 waves
    sync_conv_main<<<3752, 256, 0, stream>>>(yt, kb, ftv, ftd, bias, out);
  } else {
    fallback_kernel<<<BB * NV * ND, NFDIM, 0, stream>>>(y, ftv, ftd, kern, bias, out);
  }
}

// Round 7
// 362.452 us; speedup vs baseline: 1.0966x; 1.0966x over previous
//
#include <hip/hip_runtime.h>

#define NV 15000
#define ND 16
#define NR 3
#define NC 32
#define NFDIM 64
#define BB 2

typedef short bf16x8 __attribute__((ext_vector_type(8)));
typedef float f32x4 __attribute__((ext_vector_type(4)));
typedef unsigned short u16x8 __attribute__((ext_vector_type(8)));
typedef unsigned int u32;

// ws layout (bytes):
//   y_t  bf16 [NV][16][2][32]          : 30,720,000
//   kb   bf16 [48][4][64][8]           :    196,608
#define KB_OFF     30720000u
#define WS_NEEDED  30916608u

#define AS1 __attribute__((address_space(1)))
#define AS3 __attribute__((address_space(3)))
#define GLOAD16(gp, lp) __builtin_amdgcn_global_load_lds((AS1 const u32*)(gp), (AS3 u32*)(lp), 16, 0, 0)

__device__ __forceinline__ unsigned short f2bf(float x) {
  union { float f; unsigned int u; } cv; cv.f = x;
  unsigned int u = cv.u;
  u += 0x7FFF + ((u >> 16) & 1);          // round to nearest even
  return (unsigned short)(u >> 16);
}

// Fused prep: blocks [0,7500) convert y (B,NV,16,32) fp32 -> y_t (NV,16,B,32)
// bf16; blocks [7500,7548) build kb in MFMA B-fragment layout with f=4*col+ft:
// kb[((chunk*4+ft)*64+lane)*8+j] = kernel[chunk][k=(lane>>4)*8+j][f=(lane&15)*4+ft]
__global__ void prep_fused(const float* __restrict__ y, u16x8* __restrict__ yt,
                           const float* __restrict__ kern, unsigned short* __restrict__ kb) {
  if (blockIdx.x < 7500) {
    int tid = blockIdx.x * 256 + threadIdx.x;   // < NV*ND*BB*NC/8 = 1,920,000
    int o   = tid * 8;
    int v   = o >> 10;
    int rem = o & 1023;
    int d   = rem >> 6;
    int b   = (rem >> 5) & 1;
    int c0  = rem & 31;
    const f32x4* src = (const f32x4*)(y + (((b * NV + v) * ND + d) * NC + c0));
    f32x4 lo = src[0], hi = src[1];
    u16x8 r;
#pragma unroll
    for (int i = 0; i < 4; i++) { r[i] = f2bf(lo[i]); r[4 + i] = f2bf(hi[i]); }
    yt[tid] = r;
  } else {
    int t = (blockIdx.x - 7500) * 256 + threadIdx.x;   // [0, 48*4*64)
    if (t >= 48 * 4 * 64) return;
    int lane  = t & 63;
    int ft    = (t >> 6) & 3;
    int chunk = t >> 8;
    int q = lane >> 4;
    int f = (lane & 15) * 4 + ft;
    unsigned short* dst = kb + t * 8;
#pragma unroll
    for (int j = 0; j < 8; j++) {
      int k = q * 8 + j;
      dst[j] = f2bf(kern[(chunk * NC + k) * NFDIM + f]);
    }
  }
}

// R11: revert main to the best-measured structure (R8 loop + R9 LDS-shrink).
//
// Cross-round invariant (R0/R5/R6/R8/R9): dur == (FETCH+WRITE ~765MB) / ~3.7
// TB/s regardless of structure (reg-direct, LDS-ring depth-4, B-coop,
// counted-vmcnt). MLP ruled out (R6 depth-4 same rate; 16 waves/CU x ~32
// lines in flight >> latency-BW product). Byte reduction ruled out: R10's
// vtx-phase-split cut FETCH 645->579MB but doubled loop overhead (205->268us,
// net-negative); fp8 gather fails accuracy (2^-4 mantissa => ~16x absmax,
// threshold is 3.5x). Demand (1.47GB over 30.7MB random footprint, 48x reuse,
// L2-capacity-limited 56% hit) is structural. Main ~205us is the pattern's
// plateau on this path.
//
// This round isolates the non-main gap (~155us of the scored total): prep
// fused into one launch; if total stays ~363 the gap is harness-fixed.
//
// Per iter t (24): [vmcnt(2): slot t%3 landed, next stage in flight] ->
// s_barrier -> A(t) gather (4 loads, direct to VGPR) -> stageB(t+2) into
// dead slot (t-1)%3 -> 8 ds_read_b128 + 16 MFMA (setprio-wrapped).
__global__ __launch_bounds__(256, 4) void sync_conv_main(
    const unsigned short* __restrict__ yt, const unsigned short* __restrict__ kb,
    const int* __restrict__ ftv, const int* __restrict__ ftd,
    const float* __restrict__ bias, float* __restrict__ out) {
  // pidx is dead after the prologue; alias it over the B-ring (37,120 B
  // total -> 4 blocks/CU).
  __shared__ union ShU {
    int   pidx[16][49];      //  3,136 B (prologue only)
    short ring[3 * 4096];    // 24,576 B (3 batch-slots x 8 KB)
  } sh;
  __shared__ int pre[4][16][49];   // per-wave rotated offsets  12,544 B

  int tid  = threadIdx.x;
  int lane = tid & 63;
  int w    = tid >> 6;
  int mg   = blockIdx.x >> 2;
  int lg   = blockIdx.x & 3;
  int l    = lg * 4 + w;
  int vbase = mg * 16;

  // prologue phase 1: packed indices
  for (int t = tid; t < 16 * 48; t += 256) {
    int i = t / 48, j = t - i * 48;
    int v = vbase + i; v = v < NV ? v : NV - 1;
    sh.pidx[i][j] = ftv[v * 48 + j] * 16 + (ftd[v * 48 + j] & 15);
  }
  __syncthreads();
  // prologue phase 2: per-l pre-rotated offsets: vtx*1024 + ((ftd+l)&15)*64
#pragma unroll
  for (int wl = 0; wl < 4; wl++) {
    int ll = lg * 4 + wl;
    for (int t = tid; t < 768; t += 256) {
      int i = t / 48, j = t - i * 48;
      int p = sh.pidx[i][j];
      pre[wl][i][j] = (p >> 4) * 1024 + ((((p & 15) + ll) & 15) << 6);
    }
  }
  __syncthreads();   // pidx dead beyond this point; ring may overwrite it

  int q    = lane >> 4;
  int n    = lane & 15;
  int voff = n >> 1;
  int lane_elem = (n & 1) * 32 + q * 8;     // shorts
  const int* pre_w0 = &pre[w][voff][0];
  const int* pre_w1 = &pre[w][8 + voff][0];

  f32x4 acc[2][4];
#pragma unroll
  for (int i = 0; i < 2; i++)
#pragma unroll
    for (int j = 0; j < 4; j++) acc[i][j] = (f32x4){0.f, 0.f, 0.f, 0.f};

  // Cooperative B-stage: batch t = chunks {2t,2t+1} = 8 KB; wave w stages its
  // 2 KB quarter as two 1 KB lane-linear gl_lds loads (per-lane global stride
  // 16 B == gl_lds lane stride; LDS base wave-uniform).
  auto stageB = [&](int t, int slot) {
    const unsigned short* g = kb + t * 4096 + w * 1024 + (lane << 3);
    short* dl = sh.ring + slot * 4096 + w * 1024;
    GLOAD16(g, dl);
    GLOAD16(g + 512, dl + 512);
  };

  // Prologue: slots 0 and 1 in flight.
  stageB(0, 0);
  stageB(1, 1);

  int sl = 0;                                  // slot of batch t
#pragma unroll 3
  for (int t = 0; t < 24; t++) {
    if (t < 23) {
      asm volatile("s_waitcnt vmcnt(2)" ::: "memory");
    } else {
      asm volatile("s_waitcnt vmcnt(0)" ::: "memory");
    }
    __builtin_amdgcn_s_barrier();

    // A gather for this batch (direct to VGPR) — issue before B-stage.
    bf16x8 A[2][2];
#pragma unroll
    for (int ds = 0; ds < 2; ds++) {
      int s = 2 * t + ds;
      int j = (s & 48) | ((s + l) & 15);       // r*16 + ((e+l)&15)
      A[0][ds] = *reinterpret_cast<const bf16x8*>(yt + pre_w0[j] + lane_elem);
      A[1][ds] = *reinterpret_cast<const bf16x8*>(yt + pre_w1[j] + lane_elem);
    }

    if (t + 2 < 24) stageB(t + 2, sl == 0 ? 2 : sl - 1);   // (t+2)%3 == (t-1)%3

    const short* lb = sh.ring + sl * 4096;
    __builtin_amdgcn_s_setprio(1);
#pragma unroll
    for (int ds = 0; ds < 2; ds++) {
#pragma unroll
      for (int ft = 0; ft < 4; ft++) {
        bf16x8 bf = *reinterpret_cast<const bf16x8*>(lb + ds * 2048 + ft * 512 + (lane << 3));
        acc[0][ft] = __builtin_amdgcn_mfma_f32_16x16x32_bf16(A[0][ds], bf, acc[0][ft], 0, 0, 0);
        acc[1][ft] = __builtin_amdgcn_mfma_f32_16x16x32_bf16(A[1][ds], bf, acc[1][ft], 0, 0, 0);
      }
    }
    __builtin_amdgcn_s_setprio(0);
    sl = sl == 2 ? 0 : sl + 1;
  }

  f32x4 bv = *reinterpret_cast<const f32x4*>(bias + 4 * n);

#pragma unroll
  for (int mt = 0; mt < 2; mt++) {
#pragma unroll
    for (int reg = 0; reg < 4; reg++) {
      int m  = q * 4 + reg;
      int v  = vbase + mt * 8 + (m >> 1);
      int bb = m & 1;
      if (v < NV) {
        f32x4 x;
#pragma unroll
        for (int ft = 0; ft < 4; ft++) {
          float t = acc[mt][ft][reg] + bv[ft];   // f = 4n+ft
          x[ft] = t > 0.f ? t : 0.f;
        }
        float* dst = out + (((bb * NV + v) * ND + l) * NFDIM) + 4 * n;
        __builtin_nontemporal_store(x, (f32x4*)dst);
      }
    }
  }
}

// Slow fp32 fallback (only if ws too small).
__global__ void fallback_kernel(const float* __restrict__ y, const int* __restrict__ ftv,
                                const int* __restrict__ ftd, const float* __restrict__ kern,
                                const float* __restrict__ bias, float* __restrict__ out) {
  int idx = blockIdx.x;               // b*NV*16 + v*16 + l
  int l = idx & 15;
  int v = (idx >> 4) % NV;
  int b = idx / (NV * ND);
  int f = threadIdx.x;
  float acc = 0.f;
  for (int r = 0; r < NR; r++)
    for (int d = 0; d < ND; d++) {
      int ii = (v * NR + r) * ND + d;
      int vv = ftv[ii];
      int dd = (ftd[ii] + l) & 15;
      int dp = (d - l) & 15;
      const float* yp = y + ((b * NV + vv) * ND + dd) * NC;
      const float* kp = kern + ((r * 16 + dp) * NC) * NFDIM + f;
#pragma unroll 8
      for (int c = 0; c < NC; c++) acc += yp[c] * kp[c * NFDIM];
    }
  float x = acc + bias[f];
  out[idx * NFDIM + f] = x > 0.f ? x : 0.f;
}

extern "C" void kernel_launch(void* const* d_in, const int* in_sizes, int n_in,
                              void* d_out, int out_size, void* d_ws, size_t ws_size,
                              hipStream_t stream) {
  const float* y    = (const float*)d_in[0];
  const int*   ftv  = (const int*)d_in[1];
  const int*   ftd  = (const int*)d_in[2];
  const float* kern = (const float*)d_in[3];
  const float* bias = (const float*)d_in[4];
  float* out = (float*)d_out;

  if (ws_size >= (size_t)WS_NEEDED) {
    char* ws = (char*)d_ws;
    unsigned short* yt = (unsigned short*)ws;
    unsigned short* kb = (unsigned short*)(ws + KB_OFF);

    // 7500 y-blocks + 48 kb-blocks in one launch
    prep_fused<<<7548, 256, 0, stream>>>(y, (u16x8*)yt, kern, kb);
    // 938 m-groups (16 v each) x 4 l-groups = 3752 blocks x 4 waves
    sync_conv_main<<<3752, 256, 0, stream>>>(yt, kb, ftv, ftd, bias, out);
  } else {
    fallback_kernel<<<BB * NV * ND, NFDIM, 0, stream>>>(y, ftv, ftd, kern, bias, out);
  }
}